// Round 2
// 534.452 us; speedup vs baseline: 1.0146x; 1.0146x over previous
//
#include <hip/hip_runtime.h>

#define NROW 27
#define EDIM 5120
#define QKVDIM 15360
#define HD 1280

typedef __attribute__((ext_vector_type(8))) short bf16x8;
typedef __attribute__((ext_vector_type(4))) float f32x4;

__device__ inline short f2bf(float x) {
    unsigned u = __builtin_bit_cast(unsigned, x);
    u = (u + 0x7FFFu + ((u >> 16) & 1u)) >> 16;
    return (short)u;
}
__device__ inline float bf2f(short h) {
    unsigned u = ((unsigned)(unsigned short)h) << 16;
    return __builtin_bit_cast(float, u);
}

// ---------------------------------------------------------------------------
// C_partial[ky][27][Ntot] = X[27,Kblk] @ W[Ntot,Kblk]^T via bf16 hi/lo split.
// Register-direct W: each wave's 32 W-rows are private, so W skips LDS
// entirely -- loaded straight into B-fragment layout (lane l holds
// W[16g+(l&15)][32s+8*(l>>4)..+8]), converted fp32->bf16 hi/lo in-register.
// Only X (27 rows, shared by all 4 waves) is staged in LDS, double-buffered.
// LDS = 18 KB (was 81 KB -> 1 block/CU); now ~3 blocks/CU, 12 waves/CU,
// 8x16B loads in flight per wave the whole time -> HBM-bound streaming.
// Block: Ntile=128 x Mtile=32(27), KC=64/chunk, 256 thr = 4 waves,
// wave w owns n in [32w, 32w+32): 2x2 tiles of 16x16x32 MFMA.
// ---------------------------------------------------------------------------
#define KC 64
#define LDK 72   // 64 + 8 pad shorts -> 144 B rows (16B-aligned)

__device__ inline void loadX2(float* xbuf, const float* xp, bool xok) {
    if (xok) {
        *(float4*)&xbuf[0] = ((const float4*)xp)[0];
        *(float4*)&xbuf[4] = ((const float4*)xp)[1];
    } else {
        #pragma unroll
        for (int j = 0; j < 8; ++j) xbuf[j] = 0.f;
    }
}

// 8 float4 = chunk's W fragments for this lane: [g*4 + s*2 + half]
__device__ inline void loadWfrag(float4* wreg, const float* wp0, const float* wp1) {
    #pragma unroll
    for (int s = 0; s < 2; ++s) {
        wreg[s * 2 + 0] = *(const float4*)(wp0 + 32 * s);
        wreg[s * 2 + 1] = *(const float4*)(wp0 + 32 * s + 4);
        wreg[4 + s * 2 + 0] = *(const float4*)(wp1 + 32 * s);
        wreg[4 + s * 2 + 1] = *(const float4*)(wp1 + 32 * s + 4);
    }
}

__global__ __launch_bounds__(256, 3)
void gemm_regw(const float* __restrict__ X, const float* __restrict__ W,
               float* __restrict__ Cp, int K, int Ntot, int Kblk)
{
    __shared__ __align__(16) short Xhi[2][32][LDK];
    __shared__ __align__(16) short Xlo[2][32][LDK];

    const int tid = threadIdx.x;
    const int n0 = blockIdx.x * 128;
    const int k0 = blockIdx.y * Kblk;

    const int lane = tid & 63;
    const int wv   = tid >> 6;
    const int lm   = lane & 15;
    const int q8   = (lane >> 4) * 8;

    f32x4 acc[2][2] = {};

    // X loader: 8 threads/row, 8 floats each (rows 27..31 zero-filled)
    const int xr = tid >> 3;
    const int xk = (tid & 7) * 8;
    const bool xok = (xr < NROW);
    const float* xp = X + (size_t)(xok ? xr : 0) * K + k0 + xk;

    // W fragment pointers: rows n0+32wv+lm and +16, k at q8
    const float* wp0 = W + (size_t)(n0 + 32 * wv + lm) * K + k0 + q8;
    const float* wp1 = wp0 + (size_t)16 * K;

    float  xbuf[8];
    float4 wreg[8];

    // prologue: issue chunk-0 loads
    loadX2(xbuf, xp, xok);
    loadWfrag(wreg, wp0, wp1);

    const int nc = Kblk / KC;
    int p = 0;
    for (int c = 0; c < nc; ++c) {
        // ---- stage X chunk (fp32 -> bf16 hi/lo) into LDS buffer p ----
        {
            bf16x8 h8, l8;
            #pragma unroll
            for (int j = 0; j < 8; ++j) {
                short h = f2bf(xbuf[j]);
                h8[j] = h;
                l8[j] = f2bf(xbuf[j] - bf2f(h));
            }
            *(bf16x8*)&Xhi[p][xr][xk] = h8;
            *(bf16x8*)&Xlo[p][xr][xk] = l8;
        }

        // ---- convert W regs -> bf16 hi/lo fragments (no LDS round-trip) ----
        bf16x8 whi[2][2], wlo[2][2];   // [s][g]
        #pragma unroll
        for (int g = 0; g < 2; ++g) {
            #pragma unroll
            for (int s = 0; s < 2; ++s) {
                const float4 a = wreg[g * 4 + s * 2 + 0];
                const float4 b = wreg[g * 4 + s * 2 + 1];
                const float f[8] = {a.x, a.y, a.z, a.w, b.x, b.y, b.z, b.w};
                bf16x8 h8, l8;
                #pragma unroll
                for (int j = 0; j < 8; ++j) {
                    short h = f2bf(f[j]);
                    h8[j] = h;
                    l8[j] = f2bf(f[j] - bf2f(h));
                }
                whi[s][g] = h8;
                wlo[s][g] = l8;
            }
        }

        // ---- prefetch next chunk into regs (overlaps MFMA + other waves) ----
        if (c + 1 < nc) {
            xp  += KC;
            wp0 += KC;
            wp1 += KC;
            loadX2(xbuf, xp, xok);
            loadWfrag(wreg, wp0, wp1);
        }

        __syncthreads();

        // ---- MFMA on staged chunk ----
        #pragma unroll
        for (int s = 0; s < 2; ++s) {
            const int ko = 32 * s + q8;
            bf16x8 ah0 = *(const bf16x8*)&Xhi[p][lm][ko];
            bf16x8 ah1 = *(const bf16x8*)&Xhi[p][lm + 16][ko];
            bf16x8 al0 = *(const bf16x8*)&Xlo[p][lm][ko];
            bf16x8 al1 = *(const bf16x8*)&Xlo[p][lm + 16][ko];

            acc[0][0] = __builtin_amdgcn_mfma_f32_16x16x32_bf16(ah0, whi[s][0], acc[0][0], 0, 0, 0);
            acc[0][0] = __builtin_amdgcn_mfma_f32_16x16x32_bf16(ah0, wlo[s][0], acc[0][0], 0, 0, 0);
            acc[0][0] = __builtin_amdgcn_mfma_f32_16x16x32_bf16(al0, whi[s][0], acc[0][0], 0, 0, 0);

            acc[0][1] = __builtin_amdgcn_mfma_f32_16x16x32_bf16(ah0, whi[s][1], acc[0][1], 0, 0, 0);
            acc[0][1] = __builtin_amdgcn_mfma_f32_16x16x32_bf16(ah0, wlo[s][1], acc[0][1], 0, 0, 0);
            acc[0][1] = __builtin_amdgcn_mfma_f32_16x16x32_bf16(al0, whi[s][1], acc[0][1], 0, 0, 0);

            acc[1][0] = __builtin_amdgcn_mfma_f32_16x16x32_bf16(ah1, whi[s][0], acc[1][0], 0, 0, 0);
            acc[1][0] = __builtin_amdgcn_mfma_f32_16x16x32_bf16(ah1, wlo[s][0], acc[1][0], 0, 0, 0);
            acc[1][0] = __builtin_amdgcn_mfma_f32_16x16x32_bf16(al1, whi[s][0], acc[1][0], 0, 0, 0);

            acc[1][1] = __builtin_amdgcn_mfma_f32_16x16x32_bf16(ah1, whi[s][1], acc[1][1], 0, 0, 0);
            acc[1][1] = __builtin_amdgcn_mfma_f32_16x16x32_bf16(ah1, wlo[s][1], acc[1][1], 0, 0, 0);
            acc[1][1] = __builtin_amdgcn_mfma_f32_16x16x32_bf16(al1, whi[s][1], acc[1][1], 0, 0, 0);
        }
        p ^= 1;
    }

    const size_t base = (size_t)blockIdx.y * NROW * Ntot;
    #pragma unroll
    for (int mi = 0; mi < 2; ++mi) {
        #pragma unroll
        for (int r = 0; r < 4; ++r) {
            const int m = mi * 16 + (lane >> 4) * 4 + r;
            if (m < NROW) {
                #pragma unroll
                for (int ni = 0; ni < 2; ++ni) {
                    const int n = n0 + 32 * wv + ni * 16 + lm;
                    Cp[base + (size_t)m * Ntot + n] = acc[mi][ni][r];
                }
            }
        }
    }
}

// ---------------------------------------------------------------------------
// out[27,Ntot] = sum_ky Cp[ky] + bias [, * hertz]; optional fused adj block.
// ---------------------------------------------------------------------------
__global__ __launch_bounds__(256)
void reduce_kernel(const float* __restrict__ Cp, const float* __restrict__ bias,
                   float* __restrict__ out, int Ntot, int nky, const int* __restrict__ hz,
                   const float* __restrict__ cr, const float* __restrict__ gb,
                   float* __restrict__ adj)
{
    if (adj && blockIdx.x == gridDim.x - 1) {
        for (int t = threadIdx.x; t < NROW * NROW; t += 256) {
            const int i = t / NROW, j = t % NROW;
            float v = 0.f;
            if (i != j) {
                float z = cr[i] + cr[NROW + j] + gb[0];
                v = 1.0f / (1.0f + expf(-z));
            }
            adj[t] = v;
        }
        return;
    }
    const int idx = blockIdx.x * 256 + threadIdx.x;  // float4 index
    const int total4 = NROW * Ntot / 4;
    if (idx >= total4) return;
    float4 s = ((const float4*)Cp)[idx];
    for (int k = 1; k < nky; ++k) {
        float4 p = ((const float4*)(Cp + (size_t)k * NROW * Ntot))[idx];
        s.x += p.x; s.y += p.y; s.z += p.z; s.w += p.w;
    }
    const int n = (idx * 4) % Ntot;
    float4 b = *(const float4*)(bias + n);
    s.x += b.x; s.y += b.y; s.z += b.z; s.w += b.w;
    if (hz) {
        float h = (float)hz[0] * 0.001f;
        float sc = fminf(fmaxf(h, 0.1f), 1.0f);
        s.x *= sc; s.y *= sc; s.z *= sc; s.w *= sc;
    }
    ((float4*)out)[idx] = s;
}

// ---------------------------------------------------------------------------
// col[i] = node_flat[i]·w_n ; row[i] = hist_flat[i]·w_h
// ---------------------------------------------------------------------------
__global__ __launch_bounds__(256)
void colrow_kernel(const float* __restrict__ node, const float* __restrict__ hist,
                   const float* __restrict__ gw, float* __restrict__ cr)
{
    const int b = blockIdx.x;
    const float* x = (b < NROW) ? node + (size_t)b * EDIM : hist + (size_t)(b - NROW) * EDIM;
    const float* w = (b < NROW) ? gw + EDIM : gw;
    const int tid = threadIdx.x;
    float a = 0.f;
    for (int f = tid; f < EDIM / 4; f += 256) {
        float4 xv = ((const float4*)x)[f];
        float4 wv = ((const float4*)w)[f];
        a += xv.x * wv.x + xv.y * wv.y + xv.z * wv.z + xv.w * wv.w;
    }
    #pragma unroll
    for (int off = 32; off; off >>= 1) a += __shfl_down(a, off);
    __shared__ float red[4];
    if ((tid & 63) == 0) red[tid >> 6] = a;
    __syncthreads();
    if (tid == 0) cr[b] = red[0] + red[1] + red[2] + red[3];
}

// ---------------------------------------------------------------------------
// MHA on qkv[27, 15360] (biases already added). One block per (head, query).
// ---------------------------------------------------------------------------
__global__ __launch_bounds__(256)
void attn_kernel(const float* __restrict__ qkv, float* __restrict__ O)
{
    __shared__ float qs[HD];
    __shared__ float sc[NROW];
    __shared__ float pr[NROW];
    const int bx = blockIdx.x;
    const int h = bx & 3;
    const int i = bx >> 2;
    const int tid = threadIdx.x;

    const size_t qoff = (size_t)i * QKVDIM + (size_t)h * HD;
    for (int d = tid; d < HD; d += 256) qs[d] = qkv[qoff + d];
    __syncthreads();

    const int wid = tid >> 6, lane = tid & 63;
    for (int j = wid; j < NROW; j += 4) {
        const float* kr = qkv + (size_t)j * QKVDIM + EDIM + (size_t)h * HD;
        float a = 0.f;
        #pragma unroll
        for (int it = 0; it < 5; ++it) {
            int d4 = lane + 64 * it;
            float4 k4 = *(const float4*)(kr + 4 * d4);
            float4 q4 = *(const float4*)(qs + 4 * d4);
            a += q4.x * k4.x + q4.y * k4.y + q4.z * k4.z + q4.w * k4.w;
        }
        #pragma unroll
        for (int off = 32; off; off >>= 1) a += __shfl_down(a, off);
        if (lane == 0) sc[j] = a * 0.02795084971874737f;  // 1/sqrt(1280)
    }
    __syncthreads();

    float mxv = -1e30f;
    for (int j = 0; j < NROW; ++j) mxv = fmaxf(mxv, sc[j]);
    float s = 0.f;
    for (int j = 0; j < NROW; ++j) s += expf(sc[j] - mxv);
    if (tid < NROW) pr[tid] = expf(sc[tid] - mxv) / s;
    __syncthreads();

    for (int d4 = tid; d4 < HD / 4; d4 += 256) {
        float4 o = make_float4(0.f, 0.f, 0.f, 0.f);
        for (int j = 0; j < NROW; ++j) {
            const float4 v4 = *(const float4*)(qkv + (size_t)j * QKVDIM + 2 * EDIM + (size_t)h * HD + 4 * d4);
            const float p = pr[j];
            o.x = fmaf(p, v4.x, o.x);
            o.y = fmaf(p, v4.y, o.y);
            o.z = fmaf(p, v4.z, o.z);
            o.w = fmaf(p, v4.w, o.w);
        }
        *(float4*)(O + (size_t)i * EDIM + (size_t)h * HD + 4 * d4) = o;
    }
}

extern "C" void kernel_launch(void* const* d_in, const int* in_sizes, int n_in,
                              void* d_out, int out_size, void* d_ws, size_t ws_size,
                              hipStream_t stream)
{
    const float* node = (const float*)d_in[0];
    const float* hist = (const float*)d_in[1];
    const float* gw   = (const float*)d_in[2];
    const float* gb   = (const float*)d_in[3];
    const float* inw  = (const float*)d_in[4];
    const float* inb  = (const float*)d_in[5];
    const float* outw = (const float*)d_in[6];
    const float* outb = (const float*)d_in[7];
    const int*   hz   = (const int*)d_in[8];

    float* out = (float*)d_out;  // [0:138240) attended-out, [138240:138969) adj

    // ws layout (floats)
    float* Cp1  = (float*)d_ws;                          // 8 * 27 * 15360
    float* qkvf = Cp1 + (size_t)8 * NROW * QKVDIM;       // 27 * 15360
    float* Obuf = qkvf + (size_t)NROW * QKVDIM;          // 27 * 5120
    float* Cp2  = Obuf + (size_t)NROW * EDIM;            // 16 * 27 * 5120
    float* cr   = Cp2 + (size_t)16 * NROW * EDIM;        // 54

    colrow_kernel<<<54, 256, 0, stream>>>(node, hist, gw, cr);

    // qkv = node_flat @ in_w.T (+bias in reduce): N=15360, ksplit=8
    gemm_regw<<<dim3(120, 8), 256, 0, stream>>>(node, inw, Cp1, EDIM, QKVDIM, EDIM / 8);
    reduce_kernel<<<NROW * QKVDIM / 4 / 256, 256, 0, stream>>>(
        Cp1, inb, qkvf, QKVDIM, 8, nullptr, nullptr, nullptr, nullptr);

    attn_kernel<<<108, 256, 0, stream>>>(qkvf, Obuf);

    // out = (O @ out_w.T + out_b) * hertz: N=5120, ksplit=16; +1 block does adj
    gemm_regw<<<dim3(40, 16), 256, 0, stream>>>(Obuf, outw, Cp2, EDIM, EDIM, EDIM / 16);
    reduce_kernel<<<NROW * EDIM / 4 / 256 + 1, 256, 0, stream>>>(
        Cp2, outb, out, EDIM, 16, hz, cr, gb, out + (size_t)NROW * EDIM);
}